// Round 2
// baseline (224.754 us; speedup 1.0000x reference)
//
#include <hip/hip_runtime.h>
#include <hip/hip_bf16.h>
#include <math.h>

// Problem constants (fixed by the reference)
#define BB   8
#define NQ   256
#define NKV  1024
#define DD   256   // DQ == DK == DV == 256
#define HH   128   // hidden
#define KSPLIT 4   // k-splits per q-tile (flash-style partial softmax)
#define KCH  256   // k per split (NKV / KSPLIT)

typedef float f16v __attribute__((ext_vector_type(16)));

// ---------------------------------------------------------------------------
// Kernel 1: fused projection + exp.
//   Eq[row][h] = exp(2 * dot(Q[row,:], Wq[h,:]))   rows 0..2047
//   Ek[row][h] = exp(2 * dot(K[row,:], Wk[h,:]))   rows 0..8191
// 8-row x 128-h tile per block, 256 threads (4 waves), grid 1280 blocks
// -> ~5 blocks/CU, ~20 waves/CU. Thread = 1 row x 4 h (float4 acc).
// ---------------------------------------------------------------------------
__global__ __launch_bounds__(256) void proj_exp_kernel(
    const float* __restrict__ Q, const float* __restrict__ K,
    const float* __restrict__ Wq, const float* __restrict__ Wk,
    float* __restrict__ eqb, float* __restrict__ ekb)
{
    __shared__ __align__(16) float At[32][9];    // [d][row], 8 rows + pad
    __shared__ __align__(16) float Wt[32][132];  // [d][h], pad to 132

    const int bid = blockIdx.x;
    const bool isQ = bid < (BB * NQ / 8);        // first 256 blocks: Q part
    const float* A = isQ ? Q : K;
    const float* W = isQ ? Wq : Wk;
    float* Out     = isQ ? eqb : ekb;
    const int arow0 = (isQ ? bid : bid - (BB * NQ / 8)) * 8;

    const int tid = threadIdx.x;
    const int rc  = tid >> 5;    // 0..7 -> row
    const int hc  = tid & 31;    // 0..31 -> h = hc*4..hc*4+3

    float4 c = {0.f, 0.f, 0.f, 0.f};

    for (int dc = 0; dc < DD; dc += 32) {
        // issue global loads before the barrier (overlap with prior compute)
        float4 a4;
        if (tid < 64)
            a4 = *(const float4*)(A + (size_t)(arow0 + (tid >> 3)) * DD + dc + (tid & 7) * 4);
        float4 w4[4];
#pragma unroll
        for (int t = 0; t < 4; ++t) {
            int idx = tid + t * 256;
            int h = idx >> 3, dw = idx & 7;
            w4[t] = *(const float4*)(W + (size_t)h * DD + dc + dw * 4);
        }
        __syncthreads();   // previous iteration's LDS reads complete
        if (tid < 64) {
            int r_st = tid >> 3, dq = tid & 7;
            At[dq*4+0][r_st] = a4.x;
            At[dq*4+1][r_st] = a4.y;
            At[dq*4+2][r_st] = a4.z;
            At[dq*4+3][r_st] = a4.w;
        }
#pragma unroll
        for (int t = 0; t < 4; ++t) {
            int idx = tid + t * 256;
            int h = idx >> 3, dw = idx & 7;
            Wt[dw*4+0][h] = w4[t].x;
            Wt[dw*4+1][h] = w4[t].y;
            Wt[dw*4+2][h] = w4[t].z;
            Wt[dw*4+3][h] = w4[t].w;
        }
        __syncthreads();
#pragma unroll
        for (int d = 0; d < 32; ++d) {
            float av  = At[d][rc];
            float4 wv = *(const float4*)&Wt[d][hc * 4];
            c.x = fmaf(av, wv.x, c.x);
            c.y = fmaf(av, wv.y, c.y);
            c.z = fmaf(av, wv.z, c.z);
            c.w = fmaf(av, wv.w, c.w);
        }
    }

    float4 o;
    o.x = __expf(2.f * c.x); o.y = __expf(2.f * c.y);
    o.z = __expf(2.f * c.z); o.w = __expf(2.f * c.w);
    *(float4*)(Out + (size_t)(arow0 + rc) * HH + hc * 4) = o;
}

// ---------------------------------------------------------------------------
// Kernel 2: flash-style partial attention over a 256-wide k-slice.
// Grid: B*(NQ/8)*KSPLIT = 1024 blocks, 512 threads (8 waves).
// bid -> s = bid&3 (k-split), t = bid>>2 (q-tile); b = t>>5, q0 = (t&31)*8.
// Inactive slices (k0 >= valid_len) write zeros + (m=-1e30, l=0) and retire
// -> fine-grained dynamic load balance across CUs.
// Score phase (identical math to round 1): Wv[h]*tanh(q+k)
//   = Wv[h] - 2*Wv[h]*rcp(1 + Eq*Ek), Eq/Ek precomputed by kernel 1.
// Then per-slice masked softmax (m, l) and UNNORMALIZED partial PV -> ws.
// ---------------------------------------------------------------------------
__global__ __launch_bounds__(512) void attn_partial_kernel(
    const float* __restrict__ V, const int* __restrict__ vls,
    const float* __restrict__ Wv,
    const float* __restrict__ eqb, const float* __restrict__ ekb,
    float* __restrict__ pvb, float* __restrict__ mlb)
{
    __shared__ float sc[8][KCH];   // scores then P (8 rows x 256 k)

    const int bid  = blockIdx.x;
    const int s    = bid & (KSPLIT - 1);
    const int t    = bid >> 2;          // q-tile 0..255
    const int b    = t >> 5;
    const int q0   = (t & 31) << 3;
    const int k0   = s << 8;            // slice base
    const int r0   = t * 8;             // global row base = b*NQ + q0
    const int tid  = threadIdx.x;
    const int w    = tid >> 6;          // wave 0..7
    const int lane = tid & 63;
    const int vl   = vls[b];

    if (k0 >= vl) {
        // fully-masked slice: zero partial PV, ml = (-1e30, 0), retire.
        float4 z = {0.f, 0.f, 0.f, 0.f};
        ((float4*)(pvb + ((size_t)(r0 + w) * KSPLIT + s) * KCH))[lane] = z;
        if (lane == 0) {
            mlb[((r0 + w) * KSPLIT + s) * 2 + 0] = -1e30f;
            mlb[((r0 + w) * KSPLIT + s) * 2 + 1] = 0.f;
        }
        return;
    }

    const int qg = w & 1;                            // q-group (rows qg*4..+3)
    const int ks = ((w >> 1) << 3) + (lane >> 3);    // 0..31 k-slot
    const int hg = lane & 7;                         // h-group (h = hg*16..+15)

    const int kcnt = min(vl - k0, KCH);              // valid k in this slice
    const int nst  = (kcnt + 31) >> 5;               // 1..8 k-steps

    // Wv slice: nw2[j] = -2*Wv[hg*16+j]; swv = sum of own Wv (acc init)
    f16v nw2;
    float swv = 0.f;
#pragma unroll
    for (int i = 0; i < 4; ++i) {
        float4 v4 = *(const float4*)(Wv + hg * 16 + i * 4);
        nw2[i*4+0] = -2.f * v4.x; nw2[i*4+1] = -2.f * v4.y;
        nw2[i*4+2] = -2.f * v4.z; nw2[i*4+3] = -2.f * v4.w;
        swv += v4.x + v4.y + v4.z + v4.w;
    }

    // Eq rows in registers: 4 rows x 16 h
    f16v eqr[4];
#pragma unroll
    for (int r = 0; r < 4; ++r) {
        const float4* p = (const float4*)(eqb + (size_t)(r0 + qg*4 + r) * HH + hg * 16);
        float4 x0 = p[0], x1 = p[1], x2 = p[2], x3 = p[3];
        f16v e;
        e[0]=x0.x;e[1]=x0.y;e[2]=x0.z;e[3]=x0.w; e[4]=x1.x;e[5]=x1.y;e[6]=x1.z;e[7]=x1.w;
        e[8]=x2.x;e[9]=x2.y;e[10]=x2.z;e[11]=x2.w; e[12]=x3.x;e[13]=x3.y;e[14]=x3.z;e[15]=x3.w;
        eqr[r] = e;
    }

    const float* ekbase = ekb + ((size_t)(b * NKV) + k0) * HH + hg * 16;

    auto loadEk = [&](f16v& e, int step) {
        const float4* p = (const float4*)(ekbase + (size_t)(step * 32 + ks) * HH);
        float4 x0 = p[0], x1 = p[1], x2 = p[2], x3 = p[3];
        e[0]=x0.x;e[1]=x0.y;e[2]=x0.z;e[3]=x0.w; e[4]=x1.x;e[5]=x1.y;e[6]=x1.z;e[7]=x1.w;
        e[8]=x2.x;e[9]=x2.y;e[10]=x2.z;e[11]=x2.w; e[12]=x3.x;e[13]=x3.y;e[14]=x3.z;e[15]=x3.w;
    };

    auto body = [&](const f16v& e, int step) {
        float a0 = swv, a1 = swv, a2 = swv, a3 = swv;
#pragma unroll
        for (int j = 0; j < 16; ++j) {
            float ej = e[j];
            float t0 = fmaf(eqr[0][j], ej, 1.0f);
            float t1 = fmaf(eqr[1][j], ej, 1.0f);
            float t2 = fmaf(eqr[2][j], ej, 1.0f);
            float t3 = fmaf(eqr[3][j], ej, 1.0f);
            float r0v = __builtin_amdgcn_rcpf(t0);
            float r1v = __builtin_amdgcn_rcpf(t1);
            float r2v = __builtin_amdgcn_rcpf(t2);
            float r3v = __builtin_amdgcn_rcpf(t3);
            float nj = nw2[j];
            a0 = fmaf(nj, r0v, a0);
            a1 = fmaf(nj, r1v, a1);
            a2 = fmaf(nj, r2v, a2);
            a3 = fmaf(nj, r3v, a3);
        }
        a0 += __shfl_xor(a0, 1); a0 += __shfl_xor(a0, 2); a0 += __shfl_xor(a0, 4);
        a1 += __shfl_xor(a1, 1); a1 += __shfl_xor(a1, 2); a1 += __shfl_xor(a1, 4);
        a2 += __shfl_xor(a2, 1); a2 += __shfl_xor(a2, 2); a2 += __shfl_xor(a2, 4);
        a3 += __shfl_xor(a3, 1); a3 += __shfl_xor(a3, 2); a3 += __shfl_xor(a3, 4);
        if (hg == 0) {
            int kk = step * 32 + ks;
            sc[qg*4+0][kk] = a0;
            sc[qg*4+1][kk] = a1;
            sc[qg*4+2][kk] = a2;
            sc[qg*4+3][kk] = a3;
        }
    };

    // ---- score phase over this slice (2-deep register double-buffer)
    f16v ekA, ekB;
    loadEk(ekA, 0);
    for (int st = 0; st < nst; st += 2) {
        if (st + 1 < nst) loadEk(ekB, st + 1);
        body(ekA, st);
        if (st + 1 < nst) {
            if (st + 2 < nst) loadEk(ekA, st + 2);
            body(ekB, st + 1);
        }
    }
    __syncthreads();

    // ---- per-slice masked softmax: wave w owns row w
    {
        float m = -1e30f;
        float sv[4];
#pragma unroll
        for (int i = 0; i < 4; ++i) {
            int kk = i * 64 + lane;
            float sval = sc[w][kk];
            sv[i] = sval;
            if (k0 + kk < vl) m = fmaxf(m, sval);
        }
#pragma unroll
        for (int off = 1; off < 64; off <<= 1) m = fmaxf(m, __shfl_xor(m, off));
        float sum = 0.f;
#pragma unroll
        for (int i = 0; i < 4; ++i) {
            int kk = i * 64 + lane;
            float p = (k0 + kk < vl) ? __expf(sv[i] - m) : 0.f;
            sum += p;
            sc[w][kk] = p;
        }
#pragma unroll
        for (int off = 1; off < 64; off <<= 1) sum += __shfl_xor(sum, off);
        if (lane == 0) {
            mlb[((r0 + w) * KSPLIT + s) * 2 + 0] = m;
            mlb[((r0 + w) * KSPLIT + s) * 2 + 1] = sum;
        }
    }
    __syncthreads();

    // ---- partial PV (unnormalized): wave w owns row w; lane owns 4 v-cols
    {
        float4 acc = {0.f, 0.f, 0.f, 0.f};
        const float* vb = V + ((size_t)b * NKV + k0) * DD + lane * 4;
        const int kcnt4 = (kcnt + 3) & ~3;   // P==0 in the pad
        for (int kk = 0; kk < kcnt4; kk += 4) {
#pragma unroll
            for (int u = 0; u < 4; ++u) {
                float p = sc[w][kk + u];
                float4 vv = *(const float4*)(vb + (size_t)(kk + u) * DD);
                acc.x = fmaf(p, vv.x, acc.x);
                acc.y = fmaf(p, vv.y, acc.y);
                acc.z = fmaf(p, vv.z, acc.z);
                acc.w = fmaf(p, vv.w, acc.w);
            }
        }
        ((float4*)(pvb + ((size_t)(r0 + w) * KSPLIT + s) * KCH))[lane] = acc;
    }
}

// ---------------------------------------------------------------------------
// Kernel 3: flash merge of KSPLIT partials per q-row.
// out[r][c] = sum_s exp(m_s - M) * pv[r][s][c] / (sum_s l_s * exp(m_s - M))
// Grid 512 blocks x 256 threads (4 rows per block, lane owns 4 cols).
// ---------------------------------------------------------------------------
__global__ __launch_bounds__(256) void combine_kernel(
    const float* __restrict__ pvb, const float* __restrict__ mlb,
    float* __restrict__ out)
{
    const int tid  = threadIdx.x;
    const int r    = blockIdx.x * 4 + (tid >> 6);
    const int lane = tid & 63;

    float mv[KSPLIT], lv[KSPLIT];
#pragma unroll
    for (int s = 0; s < KSPLIT; ++s) {
        mv[s] = mlb[(r * KSPLIT + s) * 2 + 0];
        lv[s] = mlb[(r * KSPLIT + s) * 2 + 1];
    }
    float M = fmaxf(fmaxf(mv[0], mv[1]), fmaxf(mv[2], mv[3]));
    float coef[KSPLIT];
    float L = 0.f;
#pragma unroll
    for (int s = 0; s < KSPLIT; ++s) {
        coef[s] = __expf(mv[s] - M);
        L = fmaf(lv[s], coef[s], L);
    }
    float rinv = 1.0f / L;

    float4 acc = {0.f, 0.f, 0.f, 0.f};
#pragma unroll
    for (int s = 0; s < KSPLIT; ++s) {
        float4 pv = ((const float4*)(pvb + ((size_t)r * KSPLIT + s) * KCH))[lane];
        float cs = coef[s];
        acc.x = fmaf(cs, pv.x, acc.x);
        acc.y = fmaf(cs, pv.y, acc.y);
        acc.z = fmaf(cs, pv.z, acc.z);
        acc.w = fmaf(cs, pv.w, acc.w);
    }
    acc.x *= rinv; acc.y *= rinv; acc.z *= rinv; acc.w *= rinv;
    *(float4*)(out + (size_t)r * DD + lane * 4) = acc;
}

// ---------------------------------------------------------------------------
extern "C" void kernel_launch(void* const* d_in, const int* in_sizes, int n_in,
                              void* d_out, int out_size, void* d_ws, size_t ws_size,
                              hipStream_t stream) {
    const float* Q   = (const float*)d_in[0];
    const float* K   = (const float*)d_in[1];
    const float* V   = (const float*)d_in[2];
    const int*   vls = (const int*)  d_in[3];
    const float* Wq  = (const float*)d_in[4];
    const float* Wk  = (const float*)d_in[5];
    const float* Wv  = (const float*)d_in[6];
    float* out = (float*)d_out;

    // ws layout: Eq 1 MB | Ek 4 MB | pv 8 MB | ml 64 KB  (total ~13.1 MB)
    float* eq = (float*)d_ws;
    float* ek = eq + (size_t)BB * NQ * HH;
    float* pv = ek + (size_t)BB * NKV * HH;
    float* ml = pv + (size_t)BB * NQ * KSPLIT * KCH;

    proj_exp_kernel<<<(BB*NQ + BB*NKV) / 8, 256, 0, stream>>>(Q, K, Wq, Wk, eq, ek);
    attn_partial_kernel<<<BB * (NQ / 8) * KSPLIT, 512, 0, stream>>>(V, vls, Wv, eq, ek, pv, ml);
    combine_kernel<<<BB * NQ / 4, 256, 0, stream>>>(pv, ml, out);
}